// Round 1
// baseline (657.335 us; speedup 1.0000x reference)
//
#include <hip/hip_runtime.h>
#include <math.h>

namespace {
constexpr int N_ = 16, L_ = 256, S_ = 128, E_ = 128, A_ = 9, D_ = 768, H_ = 768, RO_ = 24;
constexpr int IDXW = 130; // S+2
constexpr float INV_SQRT_D = 0.03608439182435161f; // 1/sqrt(768)
} // namespace

// ---------------- gather sent_emb (N,S,D) ----------------
__global__ __launch_bounds__(192) void gather_sent_k(const float* __restrict__ all_emb,
                                                     const int* __restrict__ idxs,
                                                     float* __restrict__ sent) {
    const int n = blockIdx.x >> 7, s = blockIdx.x & 127;
    const int row = idxs[n * IDXW + s];
    const float4* src = reinterpret_cast<const float4*>(all_emb + ((size_t)(n * L_ + row)) * D_);
    float4* dst = reinterpret_cast<float4*>(sent + ((size_t)(n * S_ + s)) * D_);
    for (int i = threadIdx.x; i < D_ / 4; i += blockDim.x) dst[i] = src[i];
}

// ---------------- arg_emb[n,a,d] = sum_k all_emb[n,p0+k,d] * argw[n,k,a] ----------------
__global__ __launch_bounds__(256) void arg_emb_k(const float* __restrict__ all_emb,
                                                 const int* __restrict__ idxs,
                                                 const float* __restrict__ argw,
                                                 float* __restrict__ argE) {
    const int n = blockIdx.x;
    const int tid = threadIdx.x;
    __shared__ float wsm[A_][A_]; // [k][a]
    if (tid < A_ * A_) wsm[tid / A_][tid % A_] = argw[n * A_ * A_ + tid];
    __syncthreads();
    const int p0 = idxs[n * IDXW + S_] + 1;
    for (int d = tid; d < D_; d += 256) {
        float raw[A_];
#pragma unroll
        for (int k = 0; k < A_; ++k) raw[k] = all_emb[((size_t)n * L_ + p0 + k) * D_ + d];
#pragma unroll
        for (int a = 0; a < A_; ++a) {
            float acc = 0.f;
#pragma unroll
            for (int k = 0; k < A_; ++k) acc = fmaf(raw[k], wsm[k][a], acc);
            argE[((size_t)n * A_ + a) * D_ + d] = acc;
        }
    }
}

// ---------------- t2t[n,s,t]: mean-over-heads, row-normalize per layer, avg 3 layers ----------------
__global__ __launch_bounds__(128) void t2t_k(const float* __restrict__ attn,
                                             const int* __restrict__ idxs,
                                             float* __restrict__ t2t) {
    const int n = blockIdx.x >> 7, s = blockIdx.x & 127;
    const int t = threadIdx.x;
    const int is = idxs[n * IDXW + s], it = idxs[n * IDXW + t];
    float m[3];
#pragma unroll
    for (int l = 0; l < 3; ++l) {
        const float* base = attn + ((size_t)(l * N_ + n) * 12) * L_ * L_ + (size_t)is * L_ + it;
        float a = 0.f;
#pragma unroll
        for (int h = 0; h < 12; ++h) a += base[(size_t)h * L_ * L_];
        m[l] = a * (1.0f / 12.0f);
    }
    __shared__ float red[3][128];
    red[0][t] = m[0]; red[1][t] = m[1]; red[2][t] = m[2];
    __syncthreads();
    for (int off = 64; off; off >>= 1) {
        if (t < off) {
            red[0][t] += red[0][t + off];
            red[1][t] += red[1][t + off];
            red[2][t] += red[2][t + off];
        }
        __syncthreads();
    }
    const float v = m[0] / (red[0][0] + 1e-9f) + m[1] / (red[1][0] + 1e-9f) + m[2] / (red[2][0] + 1e-9f);
    t2t[((size_t)(n * S_ + s)) * S_ + t] = v * (1.0f / 3.0f);
}

// ---------------- batched GEMM: C[n] (128 x 768) = Aop[n] (128x128) @ X[n] (128x768) ----------------
// TRANSA: Aop[i,k] = Ab[k*ldA + i]; else Aop[i,k] = Ab[i*ldA + k]
template <bool TRANSA>
__global__ __launch_bounds__(256) void gemm_bat_k(const float* __restrict__ Abase, int ldA, long strideA,
                                                  const float* __restrict__ Xbase, long strideX,
                                                  float* __restrict__ Cbase, long strideC) {
    __shared__ __align__(16) float As[16][68];
    __shared__ __align__(16) float Bs[16][68];
    const int n = blockIdx.z;
    const float* Ab = Abase + (size_t)n * strideA;
    const float* Xb = Xbase + (size_t)n * strideX;
    float* Cb = Cbase + (size_t)n * strideC;
    const int r0 = blockIdx.x * 64, c0 = blockIdx.y * 64;
    const int tid = threadIdx.x;
    const int tx = tid & 15, ty = tid >> 4;
    float acc[4][4] = {};
    for (int k0 = 0; k0 < S_; k0 += 16) {
        if (TRANSA) {
            const int i = tid & 63, kb = tid >> 6;
#pragma unroll
            for (int c = 0; c < 4; ++c) {
                const int k = kb * 4 + c;
                As[k][i] = Ab[(size_t)(k0 + k) * ldA + r0 + i];
            }
        } else {
            const int row = tid >> 2, kq = tid & 3;
            float4 v = *reinterpret_cast<const float4*>(Ab + (size_t)(r0 + row) * ldA + k0 + kq * 4);
            As[kq * 4 + 0][row] = v.x; As[kq * 4 + 1][row] = v.y;
            As[kq * 4 + 2][row] = v.z; As[kq * 4 + 3][row] = v.w;
        }
        {
            const int jq = tid & 15, k = tid >> 4;
            float4 v = *reinterpret_cast<const float4*>(Xb + (size_t)(k0 + k) * D_ + c0 + jq * 4);
            *reinterpret_cast<float4*>(&Bs[k][jq * 4]) = v;
        }
        __syncthreads();
#pragma unroll
        for (int k = 0; k < 16; ++k) {
            float4 a4 = *reinterpret_cast<const float4*>(&As[k][ty * 4]);
            float4 b4 = *reinterpret_cast<const float4*>(&Bs[k][tx * 4]);
            const float am[4] = {a4.x, a4.y, a4.z, a4.w};
            const float bn[4] = {b4.x, b4.y, b4.z, b4.w};
#pragma unroll
            for (int m = 0; m < 4; ++m)
#pragma unroll
                for (int j = 0; j < 4; ++j) acc[m][j] = fmaf(am[m], bn[j], acc[m][j]);
        }
        __syncthreads();
    }
#pragma unroll
    for (int m = 0; m < 4; ++m) {
        const int row = r0 + ty * 4 + m;
        float4 v = make_float4(acc[m][0], acc[m][1], acc[m][2], acc[m][3]);
        *reinterpret_cast<float4*>(Cb + (size_t)row * D_ + c0 + tx * 4) = v;
    }
}

// ---------------- C (M x 768) = sum_seg Aseg (M x 768) @ W1[off_seg : off_seg+768, :] ----------------
__global__ __launch_bounds__(256) void gemm_cat3_k(const float* __restrict__ A0, const float* __restrict__ A1,
                                                   const float* __restrict__ A2, const float* __restrict__ W1,
                                                   int off0, int off1, int off2,
                                                   float* __restrict__ C, int M) {
    __shared__ __align__(16) float As[16][68];
    __shared__ __align__(16) float Bs[16][68];
    const int r0 = blockIdx.x * 64, c0 = blockIdx.y * 64;
    const int tid = threadIdx.x;
    const int tx = tid & 15, ty = tid >> 4;
    float acc[4][4] = {};
    const float* Aseg[3] = {A0, A1, A2};
    const int offs[3] = {off0, off1, off2};
    for (int seg = 0; seg < 3; ++seg) {
        const float* Ab = Aseg[seg];
        const float* Wb = W1 + (size_t)offs[seg] * H_;
        for (int k0 = 0; k0 < D_; k0 += 16) {
            const int row = tid >> 2, kq = tid & 3;
            const int grow = r0 + row;
            float4 av = make_float4(0.f, 0.f, 0.f, 0.f);
            if (grow < M) av = *reinterpret_cast<const float4*>(Ab + (size_t)grow * D_ + k0 + kq * 4);
            As[kq * 4 + 0][row] = av.x; As[kq * 4 + 1][row] = av.y;
            As[kq * 4 + 2][row] = av.z; As[kq * 4 + 3][row] = av.w;
            const int jq = tid & 15, k = tid >> 4;
            float4 bv = *reinterpret_cast<const float4*>(Wb + (size_t)(k0 + k) * H_ + c0 + jq * 4);
            *reinterpret_cast<float4*>(&Bs[k][jq * 4]) = bv;
            __syncthreads();
#pragma unroll
            for (int k2 = 0; k2 < 16; ++k2) {
                float4 a4 = *reinterpret_cast<const float4*>(&As[k2][ty * 4]);
                float4 b4 = *reinterpret_cast<const float4*>(&Bs[k2][tx * 4]);
                const float am[4] = {a4.x, a4.y, a4.z, a4.w};
                const float bn[4] = {b4.x, b4.y, b4.z, b4.w};
#pragma unroll
                for (int m = 0; m < 4; ++m)
#pragma unroll
                    for (int j = 0; j < 4; ++j) acc[m][j] = fmaf(am[m], bn[j], acc[m][j]);
            }
            __syncthreads();
        }
    }
#pragma unroll
    for (int m = 0; m < 4; ++m) {
        const int row = r0 + ty * 4 + m;
        if (row < M) {
            float4 v = make_float4(acc[m][0], acc[m][1], acc[m][2], acc[m][3]);
            *reinterpret_cast<float4*>(C + (size_t)row * H_ + c0 + tx * 4) = v;
        }
    }
}

// ---------------- w[n,e,a] = (dot(ent[n,e], arg[n,a])/sqrt(D) - 5)/2 ----------------
__global__ __launch_bounds__(256) void w_k(const float* __restrict__ ent, const float* __restrict__ argE,
                                           float* __restrict__ wout) {
    const int n = blockIdx.x >> 7, e = blockIdx.x & 127;
    const int tid = threadIdx.x;
    const float* er = ent + ((size_t)(n * E_ + e)) * D_;
    const float* ar = argE + (size_t)n * A_ * D_;
    float acc[A_] = {};
    for (int d = tid; d < D_; d += 256) {
        const float ev = er[d];
#pragma unroll
        for (int a = 0; a < A_; ++a) acc[a] = fmaf(ev, ar[(size_t)a * D_ + d], acc[a]);
    }
    const int lane = tid & 63, wv = tid >> 6;
#pragma unroll
    for (int a = 0; a < A_; ++a)
        for (int off = 32; off; off >>= 1) acc[a] += __shfl_down(acc[a], off, 64);
    __shared__ float part[A_][4];
    if (lane == 0)
        for (int a = 0; a < A_; ++a) part[a][wv] = acc[a];
    __syncthreads();
    if (tid < A_) {
        const float s = part[tid][0] + part[tid][1] + part[tid][2] + part[tid][3];
        wout[(size_t)(n * E_ + e) * A_ + tid] = (s * INV_SQRT_D - 5.0f) * 0.5f;
    }
}

// ---------------- tokA[n,e,d] = sum_a w[n,e,a]*argE[n,a,d] ----------------
__global__ __launch_bounds__(256) void tokA_k(const float* __restrict__ wbuf, const float* __restrict__ argE,
                                              float* __restrict__ tokA) {
    const int n = blockIdx.x >> 7, e = blockIdx.x & 127;
    const int tid = threadIdx.x;
    __shared__ float wl[A_];
    if (tid < A_) wl[tid] = wbuf[(size_t)(n * E_ + e) * A_ + tid];
    __syncthreads();
    const float* ar = argE + (size_t)n * A_ * D_;
    for (int d = tid; d < D_; d += 256) {
        float acc = 0.f;
#pragma unroll
        for (int a = 0; a < A_; ++a) acc = fmaf(wl[a], ar[(size_t)a * D_ + d], acc);
        tokA[((size_t)(n * E_ + e)) * D_ + d] = acc;
    }
}

// ---------------- argT[n,a,d] = sum_e w[n,e,a]*ent[n,e,d] ----------------
__global__ __launch_bounds__(256) void argT_k(const float* __restrict__ wbuf, const float* __restrict__ ent,
                                              float* __restrict__ argT) {
    const int n = blockIdx.x / A_, a = blockIdx.x % A_;
    const int tid = threadIdx.x;
    __shared__ float wl[E_];
    if (tid < E_) wl[tid] = wbuf[(size_t)(n * E_ + tid) * A_ + a];
    __syncthreads();
    const float* eb = ent + (size_t)n * E_ * D_;
    for (int d = tid; d < D_; d += 256) {
        float acc = 0.f;
        for (int e = 0; e < E_; ++e) acc = fmaf(wl[e], eb[(size_t)e * D_ + d], acc);
        argT[((size_t)(n * A_ + a)) * D_ + d] = acc;
    }
}

// ---------------- a2a softmax + u2u ----------------
__global__ __launch_bounds__(256) void u2u_k(const float* __restrict__ argE, float* __restrict__ u2u) {
    const int n = blockIdx.x;
    const int tid = threadIdx.x;
    __shared__ float P[A_][A_];
    if (tid < A_ * A_) {
        const int a = tid / A_, b = tid % A_;
        const float* pa = argE + ((size_t)n * A_ + a) * D_;
        const float* pb = argE + ((size_t)n * A_ + b) * D_;
        float acc = 0.f;
        for (int d = 0; d < D_; ++d) acc = fmaf(pa[d], pb[d], acc);
        P[a][b] = acc;
    }
    __syncthreads();
    if (tid < A_) {
        const int a = tid;
        float mx = -1e30f;
#pragma unroll
        for (int b = 0; b < A_; ++b) mx = fmaxf(mx, P[a][b]);
        float s = 0.f;
        float ex[A_];
#pragma unroll
        for (int b = 0; b < A_; ++b) { ex[b] = expf(P[a][b] - mx); s += ex[b]; }
        const float inv = 1.0f / s;
#pragma unroll
        for (int b = 0; b < A_; ++b) P[a][b] = ex[b] * inv;
    }
    __syncthreads();
    const float* ab = argE + (size_t)n * A_ * D_;
    for (int d = tid; d < D_; d += 256) {
#pragma unroll
        for (int a = 0; a < A_; ++a) {
            float acc = 0.f;
#pragma unroll
            for (int b = 0; b < A_; ++b) acc = fmaf(P[a][b], ab[(size_t)b * D_ + d], acc);
            u2u[((size_t)n * A_ + a) * D_ + d] = acc;
        }
    }
}

// ---------------- epilogue: gelu(Pe+Pa+b1)@W2 + b2, scatter into (-1e6)-filled output ----------------
__global__ __launch_bounds__(256) void score_k(const float* __restrict__ Pe, const float* __restrict__ Pa,
                                               const float* __restrict__ b1, const float* __restrict__ W2,
                                               const float* __restrict__ b2, const int* __restrict__ arg_map,
                                               float* __restrict__ out) {
    const int n = blockIdx.x >> 7, e = blockIdx.x & 127;
    const int tid = threadIdx.x;
    __shared__ float paS[A_ * H_];
    __shared__ float part[A_][4];
    float* orow = out + ((size_t)(n * E_ + e)) * RO_;
    if (tid < RO_) orow[tid] = -1000000.0f;
    for (int i = tid; i < A_ * H_; i += 256) paS[i] = Pa[(size_t)n * A_ * H_ + i];
    __syncthreads();
    const float* per = Pe + ((size_t)(n * E_ + e)) * H_;
    float acc[A_] = {};
    for (int h = tid; h < H_; h += 256) {
        const float pe = per[h] + b1[h];
        const float w2 = W2[h];
#pragma unroll
        for (int a = 0; a < A_; ++a) {
            const float x = pe + paS[a * H_ + h];
            const float g = x * 0.5f * (1.0f + erff(x * 0.70710678118654752f));
            acc[a] = fmaf(g, w2, acc[a]);
        }
    }
    const int lane = tid & 63, wv = tid >> 6;
#pragma unroll
    for (int a = 0; a < A_; ++a)
        for (int off = 32; off; off >>= 1) acc[a] += __shfl_down(acc[a], off, 64);
    if (lane == 0)
        for (int a = 0; a < A_; ++a) part[a][wv] = acc[a];
    __syncthreads();
    if (tid < A_) {
        const float s = part[tid][0] + part[tid][1] + part[tid][2] + part[tid][3] + b2[0];
        orow[arg_map[n * A_ + tid]] = s;
    }
}

extern "C" void kernel_launch(void* const* d_in, const int* in_sizes, int n_in,
                              void* d_out, int out_size, void* d_ws, size_t ws_size,
                              hipStream_t stream) {
    const float* all_emb = (const float*)d_in[0];
    const float* attn    = (const float*)d_in[1];
    const float* ent_map = (const float*)d_in[2];
    const float* argw    = (const float*)d_in[3];
    // d_in[4] is_triggers: unused (reference computes trig then deletes it)
    const float* W1 = (const float*)d_in[5];
    const float* b1 = (const float*)d_in[6];
    const float* W2 = (const float*)d_in[7];
    const float* b2 = (const float*)d_in[8];
    const int* idxs    = (const int*)d_in[9];
    const int* arg_map = (const int*)d_in[10];
    float* out = (float*)d_out;

    float* ws = (float*)d_ws;
    // Workspace layout (floats). sentPe doubles as sent_emb (phase 1) and Pe (phase 2):
    // sent_emb last read in h2h GEMM; Pe written strictly after.
    float* sentPe = ws + 0;        // N*S*D = N*E*H = 1,572,864
    float* ent    = ws + 1572864;  // N*E*D
    float* tokA   = ws + 3145728;  // N*E*D
    float* h2h    = ws + 4718592;  // N*S*D
    float* Ah2h   = ws + 6291456;  // N*E*D
    float* t2t    = ws + 7864320;  // N*S*S = 262,144
    float* argE   = ws + 8126464;  // N*A*D = 110,592
    float* wbuf   = ws + 8237056;  // N*E*A = 18,432
    float* argT   = ws + 8255488;  // N*A*D
    float* u2u    = ws + 8366080;  // N*A*D
    float* Pa     = ws + 8476672;  // N*A*H
    // total = 8,587,264 floats = 34.3 MB

    // 1. gathers
    gather_sent_k<<<N_ * S_, 192, 0, stream>>>(all_emb, idxs, sentPe);
    arg_emb_k<<<N_, 256, 0, stream>>>(all_emb, idxs, argw, argE);
    t2t_k<<<N_ * S_, 128, 0, stream>>>(attn, idxs, t2t);

    // 2. per-n GEMMs (128x128 @ 128x768)
    dim3 gb(2, 12, N_);
    // entity_emb[e,d] = sum_s ent_map[s,e] * sent[s,d]  (A transposed, ldA=E)
    gemm_bat_k<true><<<gb, 256, 0, stream>>>(ent_map, E_, (long)S_ * E_, sentPe, (long)S_ * D_, ent, (long)E_ * D_);
    // h2h[s,d] = sum_t t2t[s,t] * sent[t,d]
    gemm_bat_k<false><<<gb, 256, 0, stream>>>(t2t, S_, (long)S_ * S_, sentPe, (long)S_ * D_, h2h, (long)S_ * D_);
    // Ah2h[e,d] = sum_s ent_map[s,e] * h2h[s,d]
    gemm_bat_k<true><<<gb, 256, 0, stream>>>(ent_map, E_, (long)S_ * E_, h2h, (long)S_ * D_, Ah2h, (long)E_ * D_);

    // 3. small interaction tensors
    w_k<<<N_ * E_, 256, 0, stream>>>(ent, argE, wbuf);
    tokA_k<<<N_ * E_, 256, 0, stream>>>(wbuf, argE, tokA);
    argT_k<<<N_ * A_, 256, 0, stream>>>(wbuf, ent, argT);
    u2u_k<<<N_, 256, 0, stream>>>(argE, u2u);

    // 4. factored MLP first layer: Pe (2048x768), Pa (144x768)
    // W1 row blocks: [ent 0 | argE 768 | tokA 1536 | Ah2h 2304 | argT 3072 | u2u 3840]
    gemm_cat3_k<<<dim3(32, 12), 256, 0, stream>>>(ent, tokA, Ah2h, W1, 0, 2 * D_, 3 * D_, sentPe, N_ * E_);
    gemm_cat3_k<<<dim3(3, 12), 256, 0, stream>>>(argE, argT, u2u, W1, 1 * D_, 4 * D_, 5 * D_, Pa, N_ * A_);

    // 5. gelu + W2 + b2 + scatter (fills -1e6 then scatters 9 cols per (n,e))
    score_k<<<N_ * E_, 256, 0, stream>>>(sentPe, Pa, b1, W2, b2, arg_map, out);

    (void)in_sizes; (void)n_in; (void)out_size; (void)ws_size;
}

// Round 2
// 449.530 us; speedup vs baseline: 1.4623x; 1.4623x over previous
//
#include <hip/hip_runtime.h>
#include <math.h>

namespace {
constexpr int N_ = 16, L_ = 256, S_ = 128, E_ = 128, A_ = 9, D_ = 768, H_ = 768, RO_ = 24;
constexpr int IDXW = 130; // S+2
constexpr int K3 = 3 * D_; // 2304
constexpr int W1ROWS = 6 * D_; // 4608
constexpr float INV_SQRT_D = 0.03608439182435161f; // 1/sqrt(768)
} // namespace

using bshort8 = __attribute__((ext_vector_type(8))) short;
using f32x4v = __attribute__((ext_vector_type(4))) float;

__device__ __forceinline__ unsigned short f2bf(float f) {
    unsigned u = __builtin_bit_cast(unsigned, f);
    unsigned r = (u + 0x7fffu + ((u >> 16) & 1u)) >> 16;
    return (unsigned short)r;
}

// ---------------- gather sent_emb (N,S,D) ----------------
__global__ __launch_bounds__(192) void gather_sent_k(const float* __restrict__ all_emb,
                                                     const int* __restrict__ idxs,
                                                     float* __restrict__ sent) {
    const int n = blockIdx.x >> 7, s = blockIdx.x & 127;
    const int row = idxs[n * IDXW + s];
    const float4* src = reinterpret_cast<const float4*>(all_emb + ((size_t)(n * L_ + row)) * D_);
    float4* dst = reinterpret_cast<float4*>(sent + ((size_t)(n * S_ + s)) * D_);
    for (int i = threadIdx.x; i < D_ / 4; i += blockDim.x) dst[i] = src[i];
}

// ---------------- arg_emb[n,a,d] = sum_k all_emb[n,p0+k,d] * argw[n,k,a] ----------------
__global__ __launch_bounds__(256) void arg_emb_k(const float* __restrict__ all_emb,
                                                 const int* __restrict__ idxs,
                                                 const float* __restrict__ argw,
                                                 float* __restrict__ argE) {
    const int n = blockIdx.x;
    const int tid = threadIdx.x;
    __shared__ float wsm[A_][A_]; // [k][a]
    if (tid < A_ * A_) wsm[tid / A_][tid % A_] = argw[n * A_ * A_ + tid];
    __syncthreads();
    const int p0 = idxs[n * IDXW + S_] + 1;
    for (int d = tid; d < D_; d += 256) {
        float raw[A_];
#pragma unroll
        for (int k = 0; k < A_; ++k) raw[k] = all_emb[((size_t)n * L_ + p0 + k) * D_ + d];
#pragma unroll
        for (int a = 0; a < A_; ++a) {
            float acc = 0.f;
#pragma unroll
            for (int k = 0; k < A_; ++k) acc = fmaf(raw[k], wsm[k][a], acc);
            argE[((size_t)n * A_ + a) * D_ + d] = acc;
        }
    }
}

// ---------------- t2t[n,s,t]: mean-over-heads, row-normalize per layer, avg 3 layers ----------------
__global__ __launch_bounds__(128) void t2t_k(const float* __restrict__ attn,
                                             const int* __restrict__ idxs,
                                             float* __restrict__ t2t) {
    const int n = blockIdx.x >> 7, s = blockIdx.x & 127;
    const int t = threadIdx.x;
    const int is = idxs[n * IDXW + s], it = idxs[n * IDXW + t];
    float m[3];
#pragma unroll
    for (int l = 0; l < 3; ++l) {
        const float* base = attn + ((size_t)(l * N_ + n) * 12) * L_ * L_ + (size_t)is * L_ + it;
        float a = 0.f;
#pragma unroll
        for (int h = 0; h < 12; ++h) a += base[(size_t)h * L_ * L_];
        m[l] = a * (1.0f / 12.0f);
    }
    __shared__ float red[3][128];
    red[0][t] = m[0]; red[1][t] = m[1]; red[2][t] = m[2];
    __syncthreads();
    for (int off = 64; off; off >>= 1) {
        if (t < off) {
            red[0][t] += red[0][t + off];
            red[1][t] += red[1][t + off];
            red[2][t] += red[2][t + off];
        }
        __syncthreads();
    }
    const float v = m[0] / (red[0][0] + 1e-9f) + m[1] / (red[1][0] + 1e-9f) + m[2] / (red[2][0] + 1e-9f);
    t2t[((size_t)(n * S_ + s)) * S_ + t] = v * (1.0f / 3.0f);
}

// ---------------- batched GEMM: C[n] (128 x 768) = Aop[n] (128x128) @ X[n] (128x768) ----------------
template <bool TRANSA>
__global__ __launch_bounds__(256) void gemm_bat_k(const float* __restrict__ Abase, int ldA, long strideA,
                                                  const float* __restrict__ Xbase, long strideX,
                                                  float* __restrict__ Cbase, long strideC) {
    __shared__ __align__(16) float As[16][68];
    __shared__ __align__(16) float Bs[16][68];
    const int n = blockIdx.z;
    const float* Ab = Abase + (size_t)n * strideA;
    const float* Xb = Xbase + (size_t)n * strideX;
    float* Cb = Cbase + (size_t)n * strideC;
    const int r0 = blockIdx.x * 64, c0 = blockIdx.y * 64;
    const int tid = threadIdx.x;
    const int tx = tid & 15, ty = tid >> 4;
    float acc[4][4] = {};
    for (int k0 = 0; k0 < S_; k0 += 16) {
        if (TRANSA) {
            const int i = tid & 63, kb = tid >> 6;
#pragma unroll
            for (int c = 0; c < 4; ++c) {
                const int k = kb * 4 + c;
                As[k][i] = Ab[(size_t)(k0 + k) * ldA + r0 + i];
            }
        } else {
            const int row = tid >> 2, kq = tid & 3;
            float4 v = *reinterpret_cast<const float4*>(Ab + (size_t)(r0 + row) * ldA + k0 + kq * 4);
            As[kq * 4 + 0][row] = v.x; As[kq * 4 + 1][row] = v.y;
            As[kq * 4 + 2][row] = v.z; As[kq * 4 + 3][row] = v.w;
        }
        {
            const int jq = tid & 15, k = tid >> 4;
            float4 v = *reinterpret_cast<const float4*>(Xb + (size_t)(k0 + k) * D_ + c0 + jq * 4);
            *reinterpret_cast<float4*>(&Bs[k][jq * 4]) = v;
        }
        __syncthreads();
#pragma unroll
        for (int k = 0; k < 16; ++k) {
            float4 a4 = *reinterpret_cast<const float4*>(&As[k][ty * 4]);
            float4 b4 = *reinterpret_cast<const float4*>(&Bs[k][tx * 4]);
            const float am[4] = {a4.x, a4.y, a4.z, a4.w};
            const float bn[4] = {b4.x, b4.y, b4.z, b4.w};
#pragma unroll
            for (int m = 0; m < 4; ++m)
#pragma unroll
                for (int j = 0; j < 4; ++j) acc[m][j] = fmaf(am[m], bn[j], acc[m][j]);
        }
        __syncthreads();
    }
#pragma unroll
    for (int m = 0; m < 4; ++m) {
        const int row = r0 + ty * 4 + m;
        float4 v = make_float4(acc[m][0], acc[m][1], acc[m][2], acc[m][3]);
        *reinterpret_cast<float4*>(Cb + (size_t)row * D_ + c0 + tx * 4) = v;
    }
}

// ---------------- convert 3 fp32 [M x 768] segments -> concatenated bf16 [M x 2304] ----------------
__global__ __launch_bounds__(256) void convert_cat3_k(const float* __restrict__ A0, const float* __restrict__ A1,
                                                      const float* __restrict__ A2, short* __restrict__ dst,
                                                      int M) {
    const int total = M * K3 / 4;
    const float* segs[3] = {A0, A1, A2};
    for (int gid = blockIdx.x * 256 + threadIdx.x; gid < total; gid += gridDim.x * 256) {
        const int id4 = gid * 4;
        const int r = id4 / K3, k = id4 - r * K3;
        const int seg = k / D_;
        const float4 v = *reinterpret_cast<const float4*>(segs[seg] + (size_t)r * D_ + (k - seg * D_));
        short4 o;
        o.x = (short)f2bf(v.x); o.y = (short)f2bf(v.y);
        o.z = (short)f2bf(v.z); o.w = (short)f2bf(v.w);
        *reinterpret_cast<short4*>(dst + id4) = o;
    }
}

// ---------------- W1 [4608 x 768] fp32 -> W1t [768 x 4608] bf16 (transposed) ----------------
__global__ __launch_bounds__(256) void transpose_w1_k(const float* __restrict__ W1, short* __restrict__ W1t) {
    __shared__ float tile[64][65];
    const int k0 = blockIdx.x * 64, h0 = blockIdx.y * 64;
    const int tx = threadIdx.x & 63, ty = threadIdx.x >> 6;
#pragma unroll
    for (int i = 0; i < 16; ++i) {
        const int r = ty + i * 4;
        tile[r][tx] = W1[(size_t)(k0 + r) * H_ + h0 + tx];
    }
    __syncthreads();
#pragma unroll
    for (int i = 0; i < 16; ++i) {
        const int r = ty + i * 4;
        W1t[(size_t)(h0 + r) * W1ROWS + k0 + tx] = (short)f2bf(tile[tx][r]);
    }
}

// ---------------- MFMA: C[M x 768] fp32 = Abf[M x 2304] bf16 @ W1[segments] ----------------
// W1t is [768 x 4608] bf16 transposed; segment s of Abf's k in [s*768,(s+1)*768) maps to
// W1t columns offs[s] + (k - s*768). Tiles: 128(M) x 64(N), 4 waves, K-step 32.
__global__ __launch_bounds__(256) void mfma_cat3_k(const short* __restrict__ Abf, const short* __restrict__ W1t,
                                                   int off0, int off1, int off2,
                                                   float* __restrict__ C, int M) {
    __shared__ __align__(16) short As[128][40]; // +8 pad
    __shared__ __align__(16) short Bs[64][40];
    const int r0 = blockIdx.x * 128, c0 = blockIdx.y * 64;
    const int tid = threadIdx.x;
    const int wave = tid >> 6, lane = tid & 63;
    const int row16 = lane & 15, quad = lane >> 4;
    const int offs[3] = {off0, off1, off2};
    f32x4v acc[2][4] = {};
    for (int k0 = 0; k0 < K3; k0 += 32) {
        const int seg = k0 / D_;
        const int kg = offs[seg] + (k0 - seg * D_);
        // stage A: 128 rows x 32 k (512 chunks of 8 shorts)
#pragma unroll
        for (int i = 0; i < 2; ++i) {
            const int idx = tid + 256 * i;
            const int r = idx >> 2, q = idx & 3;
            bshort8 av = {};
            const int gr = r0 + r;
            if (gr < M) av = *reinterpret_cast<const bshort8*>(Abf + (size_t)gr * K3 + k0 + q * 8);
            *reinterpret_cast<bshort8*>(&As[r][q * 8]) = av;
        }
        // stage B: 64 n-rows x 32 k
        {
            const int nn = tid >> 2, q = tid & 3;
            bshort8 bv = *reinterpret_cast<const bshort8*>(W1t + (size_t)(c0 + nn) * W1ROWS + kg + q * 8);
            *reinterpret_cast<bshort8*>(&Bs[nn][q * 8]) = bv;
        }
        __syncthreads();
        bshort8 a[2], b[4];
#pragma unroll
        for (int mi = 0; mi < 2; ++mi)
            a[mi] = *reinterpret_cast<const bshort8*>(&As[wave * 32 + mi * 16 + row16][quad * 8]);
#pragma unroll
        for (int ni = 0; ni < 4; ++ni)
            b[ni] = *reinterpret_cast<const bshort8*>(&Bs[ni * 16 + row16][quad * 8]);
#pragma unroll
        for (int mi = 0; mi < 2; ++mi)
#pragma unroll
            for (int ni = 0; ni < 4; ++ni)
                acc[mi][ni] = __builtin_amdgcn_mfma_f32_16x16x32_bf16(a[mi], b[ni], acc[mi][ni], 0, 0, 0);
        __syncthreads();
    }
    // C/D layout: col = lane&15, row = quad*4 + reg
#pragma unroll
    for (int mi = 0; mi < 2; ++mi) {
#pragma unroll
        for (int ni = 0; ni < 4; ++ni) {
            const int rbase = r0 + wave * 32 + mi * 16 + quad * 4;
            const int col = c0 + ni * 16 + row16;
#pragma unroll
            for (int t = 0; t < 4; ++t) {
                const int r = rbase + t;
                if (r < M) C[(size_t)r * H_ + col] = acc[mi][ni][t];
            }
        }
    }
}

// ---------------- w[n,e,a] = (dot(ent[n,e], arg[n,a])/sqrt(D) - 5)/2 ----------------
__global__ __launch_bounds__(256) void w_k(const float* __restrict__ ent, const float* __restrict__ argE,
                                           float* __restrict__ wout) {
    const int n = blockIdx.x >> 7, e = blockIdx.x & 127;
    const int tid = threadIdx.x;
    const float* er = ent + ((size_t)(n * E_ + e)) * D_;
    const float* ar = argE + (size_t)n * A_ * D_;
    float acc[A_] = {};
    for (int d = tid; d < D_; d += 256) {
        const float ev = er[d];
#pragma unroll
        for (int a = 0; a < A_; ++a) acc[a] = fmaf(ev, ar[(size_t)a * D_ + d], acc[a]);
    }
    const int lane = tid & 63, wv = tid >> 6;
#pragma unroll
    for (int a = 0; a < A_; ++a)
        for (int off = 32; off; off >>= 1) acc[a] += __shfl_down(acc[a], off, 64);
    __shared__ float part[A_][4];
    if (lane == 0)
        for (int a = 0; a < A_; ++a) part[a][wv] = acc[a];
    __syncthreads();
    if (tid < A_) {
        const float s = part[tid][0] + part[tid][1] + part[tid][2] + part[tid][3];
        wout[(size_t)(n * E_ + e) * A_ + tid] = (s * INV_SQRT_D - 5.0f) * 0.5f;
    }
}

// ---------------- tokA[n,e,d] = sum_a w[n,e,a]*argE[n,a,d] ----------------
__global__ __launch_bounds__(256) void tokA_k(const float* __restrict__ wbuf, const float* __restrict__ argE,
                                              float* __restrict__ tokA) {
    const int n = blockIdx.x >> 7, e = blockIdx.x & 127;
    const int tid = threadIdx.x;
    __shared__ float wl[A_];
    if (tid < A_) wl[tid] = wbuf[(size_t)(n * E_ + e) * A_ + tid];
    __syncthreads();
    const float* ar = argE + (size_t)n * A_ * D_;
    for (int d = tid; d < D_; d += 256) {
        float acc = 0.f;
#pragma unroll
        for (int a = 0; a < A_; ++a) acc = fmaf(wl[a], ar[(size_t)a * D_ + d], acc);
        tokA[((size_t)(n * E_ + e)) * D_ + d] = acc;
    }
}

// ---------------- argT[n,a,d] = sum_e w[n,e,a]*ent[n,e,d] ----------------
__global__ __launch_bounds__(256) void argT_k(const float* __restrict__ wbuf, const float* __restrict__ ent,
                                              float* __restrict__ argT) {
    const int n = blockIdx.x / A_, a = blockIdx.x % A_;
    const int tid = threadIdx.x;
    __shared__ float wl[E_];
    if (tid < E_) wl[tid] = wbuf[(size_t)(n * E_ + tid) * A_ + a];
    __syncthreads();
    const float* eb = ent + (size_t)n * E_ * D_;
    for (int d = tid; d < D_; d += 256) {
        float acc = 0.f;
        for (int e = 0; e < E_; ++e) acc = fmaf(wl[e], eb[(size_t)e * D_ + d], acc);
        argT[((size_t)(n * A_ + a)) * D_ + d] = acc;
    }
}

// ---------------- a2a softmax + u2u ----------------
__global__ __launch_bounds__(256) void u2u_k(const float* __restrict__ argE, float* __restrict__ u2u) {
    const int n = blockIdx.x;
    const int tid = threadIdx.x;
    __shared__ float P[A_][A_];
    if (tid < A_ * A_) {
        const int a = tid / A_, b = tid % A_;
        const float* pa = argE + ((size_t)n * A_ + a) * D_;
        const float* pb = argE + ((size_t)n * A_ + b) * D_;
        float acc = 0.f;
        for (int d = 0; d < D_; ++d) acc = fmaf(pa[d], pb[d], acc);
        P[a][b] = acc;
    }
    __syncthreads();
    if (tid < A_) {
        const int a = tid;
        float mx = -1e30f;
#pragma unroll
        for (int b = 0; b < A_; ++b) mx = fmaxf(mx, P[a][b]);
        float s = 0.f;
        float ex[A_];
#pragma unroll
        for (int b = 0; b < A_; ++b) { ex[b] = expf(P[a][b] - mx); s += ex[b]; }
        const float inv = 1.0f / s;
#pragma unroll
        for (int b = 0; b < A_; ++b) P[a][b] = ex[b] * inv;
    }
    __syncthreads();
    const float* ab = argE + (size_t)n * A_ * D_;
    for (int d = tid; d < D_; d += 256) {
#pragma unroll
        for (int a = 0; a < A_; ++a) {
            float acc = 0.f;
#pragma unroll
            for (int b = 0; b < A_; ++b) acc = fmaf(P[a][b], ab[(size_t)b * D_ + d], acc);
            u2u[((size_t)n * A_ + a) * D_ + d] = acc;
        }
    }
}

// ---------------- epilogue: gelu(Pe+Pa+b1)@W2 + b2, scatter into (-1e6)-filled output ----------------
__global__ __launch_bounds__(256) void score_k(const float* __restrict__ Pe, const float* __restrict__ Pa,
                                               const float* __restrict__ b1, const float* __restrict__ W2,
                                               const float* __restrict__ b2, const int* __restrict__ arg_map,
                                               float* __restrict__ out) {
    const int n = blockIdx.x >> 7, e = blockIdx.x & 127;
    const int tid = threadIdx.x;
    __shared__ float paS[A_ * H_];
    __shared__ float part[A_][4];
    float* orow = out + ((size_t)(n * E_ + e)) * RO_;
    if (tid < RO_) orow[tid] = -1000000.0f;
    for (int i = tid; i < A_ * H_; i += 256) paS[i] = Pa[(size_t)n * A_ * H_ + i];
    __syncthreads();
    const float* per = Pe + ((size_t)(n * E_ + e)) * H_;
    float acc[A_] = {};
    for (int h = tid; h < H_; h += 256) {
        const float pe = per[h] + b1[h];
        const float w2 = W2[h];
#pragma unroll
        for (int a = 0; a < A_; ++a) {
            const float x = pe + paS[a * H_ + h];
            const float g = x * 0.5f * (1.0f + erff(x * 0.70710678118654752f));
            acc[a] = fmaf(g, w2, acc[a]);
        }
    }
    const int lane = tid & 63, wv = tid >> 6;
#pragma unroll
    for (int a = 0; a < A_; ++a)
        for (int off = 32; off; off >>= 1) acc[a] += __shfl_down(acc[a], off, 64);
    if (lane == 0)
        for (int a = 0; a < A_; ++a) part[a][wv] = acc[a];
    __syncthreads();
    if (tid < A_) {
        const float s = part[tid][0] + part[tid][1] + part[tid][2] + part[tid][3] + b2[0];
        orow[arg_map[n * A_ + tid]] = s;
    }
}

extern "C" void kernel_launch(void* const* d_in, const int* in_sizes, int n_in,
                              void* d_out, int out_size, void* d_ws, size_t ws_size,
                              hipStream_t stream) {
    const float* all_emb = (const float*)d_in[0];
    const float* attn    = (const float*)d_in[1];
    const float* ent_map = (const float*)d_in[2];
    const float* argw    = (const float*)d_in[3];
    // d_in[4] is_triggers: unused (reference computes trig then deletes it)
    const float* W1 = (const float*)d_in[5];
    const float* b1 = (const float*)d_in[6];
    const float* W2 = (const float*)d_in[7];
    const float* b2 = (const float*)d_in[8];
    const int* idxs    = (const int*)d_in[9];
    const int* arg_map = (const int*)d_in[10];
    float* out = (float*)d_out;

    float* ws = (float*)d_ws;
    // Workspace layout (float units). sentPe doubles as sent_emb (phase 1) and Pe (phase 2).
    float* sentPe = ws + 0;        // N*S*D = N*E*H = 1,572,864
    float* ent    = ws + 1572864;  // N*E*D
    float* tokA   = ws + 3145728;  // N*E*D
    float* h2h    = ws + 4718592;  // N*S*D
    float* Ah2h   = ws + 6291456;  // N*E*D
    float* t2t    = ws + 7864320;  // N*S*S = 262,144
    float* argE   = ws + 8126464;  // N*A*D = 110,592
    float* wbuf   = ws + 8237056;  // N*E*A = 18,432
    float* argT   = ws + 8255488;  // N*A*D
    float* u2u    = ws + 8366080;  // N*A*D
    float* Pa     = ws + 8476672;  // N*A*H
    short* W1t    = (short*)(ws + 8587264);   // 768*4608 shorts  (1,769,472 float-slots)
    short* AbfPe  = (short*)(ws + 10356736);  // 2048*2304 shorts (2,359,296 float-slots)
    short* AbfPa  = (short*)(ws + 12716032);  // 144*2304 shorts  (165,888 float-slots)
    // total = 12,881,920 floats = 51.5 MB

    // 1. gathers + W1 transpose/convert (independent)
    gather_sent_k<<<N_ * S_, 192, 0, stream>>>(all_emb, idxs, sentPe);
    arg_emb_k<<<N_, 256, 0, stream>>>(all_emb, idxs, argw, argE);
    t2t_k<<<N_ * S_, 128, 0, stream>>>(attn, idxs, t2t);
    transpose_w1_k<<<dim3(W1ROWS / 64, H_ / 64), 256, 0, stream>>>(W1, W1t);

    // 2. per-n GEMMs (128x128 @ 128x768), fp32 vector
    dim3 gb(2, 12, N_);
    gemm_bat_k<true><<<gb, 256, 0, stream>>>(ent_map, E_, (long)S_ * E_, sentPe, (long)S_ * D_, ent, (long)E_ * D_);
    gemm_bat_k<false><<<gb, 256, 0, stream>>>(t2t, S_, (long)S_ * S_, sentPe, (long)S_ * D_, h2h, (long)S_ * D_);
    gemm_bat_k<true><<<gb, 256, 0, stream>>>(ent_map, E_, (long)S_ * E_, h2h, (long)S_ * D_, Ah2h, (long)E_ * D_);

    // 3. small interaction tensors
    w_k<<<N_ * E_, 256, 0, stream>>>(ent, argE, wbuf);
    tokA_k<<<N_ * E_, 256, 0, stream>>>(wbuf, argE, tokA);
    argT_k<<<N_ * A_, 256, 0, stream>>>(wbuf, ent, argT);
    u2u_k<<<N_, 256, 0, stream>>>(argE, u2u);

    // 4. convert MLP GEMM inputs to bf16
    convert_cat3_k<<<1024, 256, 0, stream>>>(ent, tokA, Ah2h, AbfPe, N_ * E_);
    convert_cat3_k<<<324, 256, 0, stream>>>(argE, argT, u2u, AbfPa, N_ * A_);

    // 5. factored MLP first layer via bf16 MFMA
    // W1 row blocks: [ent 0 | argE 768 | tokA 1536 | Ah2h 2304 | argT 3072 | u2u 3840]
    mfma_cat3_k<<<dim3(16, 12), 256, 0, stream>>>(AbfPe, W1t, 0, 2 * D_, 3 * D_, sentPe, N_ * E_);
    mfma_cat3_k<<<dim3(2, 12), 256, 0, stream>>>(AbfPa, W1t, 1 * D_, 4 * D_, 5 * D_, Pa, N_ * A_);

    // 6. gelu + W2 + b2 + scatter
    score_k<<<N_ * E_, 256, 0, stream>>>(sentPe, Pa, b1, W2, b2, arg_map, out);

    (void)in_sizes; (void)n_in; (void)out_size; (void)ws_size;
}

// Round 3
// 367.053 us; speedup vs baseline: 1.7908x; 1.2247x over previous
//
#include <hip/hip_runtime.h>
#include <math.h>

namespace {
constexpr int N_ = 16, L_ = 256, S_ = 128, E_ = 128, A_ = 9, D_ = 768, H_ = 768, RO_ = 24;
constexpr int IDXW = 130;       // S+2
constexpr int W1R = 6 * D_;     // 4608
constexpr float INV_SQRT_D = 0.03608439182435161f; // 1/sqrt(768)
} // namespace

using bshort8 = __attribute__((ext_vector_type(8))) short;
using f32x4v = __attribute__((ext_vector_type(4))) float;

__device__ __forceinline__ unsigned short f2bf(float f) {
    unsigned u = __builtin_bit_cast(unsigned, f);
    return (unsigned short)((u + 0x7fffu + ((u >> 16) & 1u)) >> 16);
}

// ---- gather + transpose + bf16: sentT[n][d][s] = all_emb[n][idx[s]][d] ----
__global__ __launch_bounds__(256) void gatherT_k(const float* __restrict__ all_emb,
                                                 const int* __restrict__ idxs,
                                                 unsigned short* __restrict__ sentT) {
    const int n = blockIdx.x, d0 = blockIdx.y * 64;
    __shared__ unsigned short tile[64][132];
#pragma unroll
    for (int it = 0; it < 8; ++it) {
        const int lin = threadIdx.x + 256 * it;      // 2048 float4 chunks
        const int s = lin >> 4, dq = (lin & 15) * 4;
        const int row = idxs[n * IDXW + s];
        const float4 v = *reinterpret_cast<const float4*>(all_emb + ((size_t)(n * L_ + row)) * D_ + d0 + dq);
        tile[dq + 0][s] = f2bf(v.x); tile[dq + 1][s] = f2bf(v.y);
        tile[dq + 2][s] = f2bf(v.z); tile[dq + 3][s] = f2bf(v.w);
    }
    __syncthreads();
#pragma unroll
    for (int it = 0; it < 8; ++it) {
        const int lin = threadIdx.x + 256 * it;      // 2048 ushort4 chunks
        const int d = lin >> 5, s4 = (lin & 31) * 4;
        ushort4 v = {tile[d][s4], tile[d][s4 + 1], tile[d][s4 + 2], tile[d][s4 + 3]};
        *reinterpret_cast<ushort4*>(sentT + ((size_t)(n * D_) + d0 + d) * S_ + s4) = v;
    }
}

// ---- transpose + bf16: entmapT[n][e][s] = ent_map[n][s][e] ----
__global__ __launch_bounds__(256) void entmapT_k(const float* __restrict__ ent_map,
                                                 unsigned short* __restrict__ entmapT) {
    const int n = blockIdx.x;
    __shared__ unsigned short tile[128][132];
#pragma unroll
    for (int it = 0; it < 16; ++it) {
        const int lin = threadIdx.x + 256 * it;      // 4096 float4 chunks
        const int s = lin >> 5, eq = (lin & 31) * 4;
        const float4 v = *reinterpret_cast<const float4*>(ent_map + ((size_t)(n * S_ + s)) * E_ + eq);
        tile[eq + 0][s] = f2bf(v.x); tile[eq + 1][s] = f2bf(v.y);
        tile[eq + 2][s] = f2bf(v.z); tile[eq + 3][s] = f2bf(v.w);
    }
    __syncthreads();
#pragma unroll
    for (int it = 0; it < 16; ++it) {
        const int lin = threadIdx.x + 256 * it;      // 4096 ushort4 chunks
        const int e = lin >> 5, s4 = (lin & 31) * 4;
        ushort4 v = {tile[e][s4], tile[e][s4 + 1], tile[e][s4 + 2], tile[e][s4 + 3]};
        *reinterpret_cast<ushort4*>(entmapT + ((size_t)(n * E_) + e) * S_ + s4) = v;
    }
}

// ---- W1 [4608 x 768] fp32 -> W1t [768 x 4608] bf16 ----
__global__ __launch_bounds__(256) void transpose_w1_k(const float* __restrict__ W1, short* __restrict__ W1t) {
    __shared__ float tile[64][65];
    const int k0 = blockIdx.x * 64, h0 = blockIdx.y * 64;
    const int tx = threadIdx.x & 63, ty = threadIdx.x >> 6;
#pragma unroll
    for (int i = 0; i < 16; ++i) {
        const int r = ty + i * 4;
        tile[r][tx] = W1[(size_t)(k0 + r) * H_ + h0 + tx];
    }
    __syncthreads();
#pragma unroll
    for (int i = 0; i < 16; ++i) {
        const int r = ty + i * 4;
        W1t[(size_t)(h0 + r) * W1R + k0 + tx] = (short)f2bf(tile[tx][r]);
    }
}

// ---- t2t[n,s,t] (bf16 out): coalesced LDS row staging ----
__global__ __launch_bounds__(128) void t2t_k(const float* __restrict__ attn,
                                             const int* __restrict__ idxs,
                                             unsigned short* __restrict__ t2tbf) {
    const int n = blockIdx.x >> 7, s = blockIdx.x & 127;
    const int t = threadIdx.x;
    const int is = idxs[n * IDXW + s], it = idxs[n * IDXW + t];
    __shared__ float rows[12][256];
    __shared__ float red[3][128];
    float m[3];
#pragma unroll
    for (int l = 0; l < 3; ++l) {
        const float* base = attn + ((size_t)((l * N_ + n) * 12)) * (L_ * L_) + (size_t)is * L_;
#pragma unroll
        for (int j = 0; j < 6; ++j) {
            const int lin = t + 128 * j;            // 768 float4 chunks
            const int h = lin >> 6, c4 = (lin & 63) * 4;
            *reinterpret_cast<float4*>(&rows[h][c4]) =
                *reinterpret_cast<const float4*>(base + (size_t)h * (L_ * L_) + c4);
        }
        __syncthreads();
        float v = 0.f;
#pragma unroll
        for (int h = 0; h < 12; ++h) v += rows[h][it];
        m[l] = v * (1.0f / 12.0f);
        __syncthreads();
    }
    red[0][t] = m[0]; red[1][t] = m[1]; red[2][t] = m[2];
    __syncthreads();
    for (int off = 64; off; off >>= 1) {
        if (t < off) {
            red[0][t] += red[0][t + off];
            red[1][t] += red[1][t + off];
            red[2][t] += red[2][t + off];
        }
        __syncthreads();
    }
    const float v = m[0] / (red[0][0] + 1e-9f) + m[1] / (red[1][0] + 1e-9f) + m[2] / (red[2][0] + 1e-9f);
    t2tbf[((size_t)(n * S_ + s)) * S_ + t] = f2bf(v * (1.0f / 3.0f));
}

// ---- fused arg_emb + a2a softmax + u2u ----
__global__ __launch_bounds__(256) void arg_u2u_k(const float* __restrict__ all_emb,
                                                 const int* __restrict__ idxs,
                                                 const float* __restrict__ argw,
                                                 float* __restrict__ argE,
                                                 unsigned short* __restrict__ argEbf,
                                                 unsigned short* __restrict__ u2ubf) {
    const int n = blockIdx.x, tid = threadIdx.x;
    __shared__ float wsm[A_][A_];
    __shared__ float part[45][4];
    __shared__ float Psm[A_][A_];
    if (tid < A_ * A_) wsm[tid / A_][tid % A_] = argw[n * A_ * A_ + tid];
    __syncthreads();
    const int p0 = idxs[n * IDXW + S_] + 1;
    float pp[45] = {};
    float vals[3][A_];
#pragma unroll
    for (int c = 0; c < 3; ++c) {
        const int d = tid + 256 * c;
        float raw[A_];
#pragma unroll
        for (int k = 0; k < A_; ++k) raw[k] = all_emb[((size_t)(n * L_ + p0 + k)) * D_ + d];
#pragma unroll
        for (int a = 0; a < A_; ++a) {
            float acc = 0.f;
#pragma unroll
            for (int k = 0; k < A_; ++k) acc = fmaf(raw[k], wsm[k][a], acc);
            vals[c][a] = acc;
            argE[((size_t)(n * A_ + a)) * D_ + d] = acc;
            argEbf[((size_t)(n * A_ + a)) * D_ + d] = f2bf(acc);
        }
        int p = 0;
#pragma unroll
        for (int a = 0; a < A_; ++a)
#pragma unroll
            for (int b = a; b < A_; ++b) pp[p++] += vals[c][a] * vals[c][b];
    }
    const int lane = tid & 63, wv = tid >> 6;
#pragma unroll
    for (int p = 0; p < 45; ++p) {
        float v = pp[p];
        for (int off = 32; off; off >>= 1) v += __shfl_down(v, off, 64);
        if (lane == 0) part[p][wv] = v;
    }
    __syncthreads();
    if (tid < 45) part[tid][0] = part[tid][0] + part[tid][1] + part[tid][2] + part[tid][3];
    __syncthreads();
    if (tid < A_) {
        const int a = tid;
        float v[A_], mx = -1e30f;
#pragma unroll
        for (int b = 0; b < A_; ++b) {
            const int lo = a < b ? a : b, hi = a < b ? b : a;
            v[b] = part[lo * (19 - lo) / 2 + hi - lo][0];
            mx = fmaxf(mx, v[b]);
        }
        float s = 0.f;
#pragma unroll
        for (int b = 0; b < A_; ++b) { v[b] = expf(v[b] - mx); s += v[b]; }
        const float inv = 1.0f / s;
#pragma unroll
        for (int b = 0; b < A_; ++b) Psm[a][b] = v[b] * inv;
    }
    __syncthreads();
#pragma unroll
    for (int c = 0; c < 3; ++c) {
        const int d = tid + 256 * c;
#pragma unroll
        for (int a = 0; a < A_; ++a) {
            float acc = 0.f;
#pragma unroll
            for (int b = 0; b < A_; ++b) acc = fmaf(Psm[a][b], vals[c][b], acc);
            u2ubf[((size_t)(n * A_ + a)) * D_ + d] = f2bf(acc);
        }
    }
}

// ---- batched MFMA: C[n](128x768) = A[n](128x128, bf16, k-consecutive) @ B (from BT[n][768][128]) ----
// MODE 0: store fp32 row-major + bf16 row-major; MODE 1: store bf16 transposed [768][128]; MODE 2: bf16 row-major
template <int MODE>
__global__ __launch_bounds__(256) void gemm128_k(const unsigned short* __restrict__ Ab,
                                                 const unsigned short* __restrict__ BTb,
                                                 float* __restrict__ Cf,
                                                 unsigned short* __restrict__ Cb) {
    __shared__ __align__(16) short As[128][40];
    __shared__ __align__(16) short Bs[64][40];
    const int n = blockIdx.y, c0 = blockIdx.x * 64;
    const unsigned short* A = Ab + (size_t)n * S_ * S_;
    const unsigned short* BT = BTb + (size_t)n * D_ * S_;
    const int tid = threadIdx.x;
    const int wave = tid >> 6, lane = tid & 63;
    const int row16 = lane & 15, quad = lane >> 4;
    f32x4v acc[2][4] = {};
    for (int k0 = 0; k0 < S_; k0 += 32) {
#pragma unroll
        for (int i = 0; i < 2; ++i) {
            const int idx = tid + 256 * i;
            const int r = idx >> 2, q = idx & 3;
            *reinterpret_cast<bshort8*>(&As[r][q * 8]) =
                *reinterpret_cast<const bshort8*>(A + (size_t)r * S_ + k0 + q * 8);
        }
        {
            const int col = tid >> 2, q = tid & 3;
            *reinterpret_cast<bshort8*>(&Bs[col][q * 8]) =
                *reinterpret_cast<const bshort8*>(BT + (size_t)(c0 + col) * S_ + k0 + q * 8);
        }
        __syncthreads();
        bshort8 a[2], b[4];
#pragma unroll
        for (int mi = 0; mi < 2; ++mi)
            a[mi] = *reinterpret_cast<const bshort8*>(&As[wave * 32 + mi * 16 + row16][quad * 8]);
#pragma unroll
        for (int ni = 0; ni < 4; ++ni)
            b[ni] = *reinterpret_cast<const bshort8*>(&Bs[ni * 16 + row16][quad * 8]);
#pragma unroll
        for (int mi = 0; mi < 2; ++mi)
#pragma unroll
            for (int ni = 0; ni < 4; ++ni)
                acc[mi][ni] = __builtin_amdgcn_mfma_f32_16x16x32_bf16(a[mi], b[ni], acc[mi][ni], 0, 0, 0);
        __syncthreads();
    }
#pragma unroll
    for (int mi = 0; mi < 2; ++mi) {
#pragma unroll
        for (int ni = 0; ni < 4; ++ni) {
            const int rbase = wave * 32 + mi * 16 + quad * 4;
            const int col = c0 + ni * 16 + row16;
            if (MODE == 1) {
                ushort4 v = {f2bf(acc[mi][ni][0]), f2bf(acc[mi][ni][1]),
                             f2bf(acc[mi][ni][2]), f2bf(acc[mi][ni][3])};
                *reinterpret_cast<ushort4*>(Cb + (size_t)n * D_ * S_ + (size_t)col * S_ + rbase) = v;
            } else {
#pragma unroll
                for (int t = 0; t < 4; ++t) {
                    const size_t o = ((size_t)n * S_ + rbase + t) * D_ + col;
                    if (MODE == 0) { Cf[o] = acc[mi][ni][t]; Cb[o] = f2bf(acc[mi][ni][t]); }
                    else Cb[o] = f2bf(acc[mi][ni][t]);
                }
            }
        }
    }
}

// ---- fused w + tokA ----
__global__ __launch_bounds__(256) void w_tokA_k(const float* __restrict__ ent, const float* __restrict__ argE,
                                                float* __restrict__ wbuf, unsigned short* __restrict__ tokAbf) {
    const int n = blockIdx.x >> 7, e = blockIdx.x & 127;
    const int tid = threadIdx.x;
    const float* er = ent + ((size_t)(n * E_ + e)) * D_;
    const float* ar = argE + (size_t)n * A_ * D_;
    float acc[A_] = {};
    for (int d = tid; d < D_; d += 256) {
        const float ev = er[d];
#pragma unroll
        for (int a = 0; a < A_; ++a) acc[a] = fmaf(ev, ar[(size_t)a * D_ + d], acc[a]);
    }
    const int lane = tid & 63, wv = tid >> 6;
#pragma unroll
    for (int a = 0; a < A_; ++a)
        for (int off = 32; off; off >>= 1) acc[a] += __shfl_down(acc[a], off, 64);
    __shared__ float part[A_][4];
    __shared__ float wl[A_];
    if (lane == 0)
        for (int a = 0; a < A_; ++a) part[a][wv] = acc[a];
    __syncthreads();
    if (tid < A_) {
        const float s = part[tid][0] + part[tid][1] + part[tid][2] + part[tid][3];
        const float w = (s * INV_SQRT_D - 5.0f) * 0.5f;
        wl[tid] = w;
        wbuf[(size_t)(n * E_ + e) * A_ + tid] = w;
    }
    __syncthreads();
    for (int d = tid; d < D_; d += 256) {
        float s = 0.f;
#pragma unroll
        for (int a = 0; a < A_; ++a) s = fmaf(wl[a], ar[(size_t)a * D_ + d], s);
        tokAbf[((size_t)(n * E_ + e)) * D_ + d] = f2bf(s);
    }
}

// ---- argT[n,a,d] = sum_e w[n,e,a]*ent[n,e,d] (bf16 out) ----
__global__ __launch_bounds__(256) void argT_k(const float* __restrict__ wbuf, const float* __restrict__ ent,
                                              unsigned short* __restrict__ argTbf) {
    const int n = blockIdx.x / A_, a = blockIdx.x % A_;
    const int tid = threadIdx.x;
    __shared__ float wl[E_];
    if (tid < E_) wl[tid] = wbuf[(size_t)(n * E_ + tid) * A_ + a];
    __syncthreads();
    const float* eb = ent + (size_t)n * E_ * D_;
    for (int d = tid; d < D_; d += 256) {
        float acc = 0.f;
        for (int e = 0; e < E_; ++e) acc = fmaf(wl[e], eb[(size_t)e * D_ + d], acc);
        argTbf[((size_t)(n * A_ + a)) * D_ + d] = f2bf(acc);
    }
}

// ---- MLP layer 1: Pe (2048x768) and Pa (144x768) in one grid ----
__global__ __launch_bounds__(256) void mfma_mlp_k(const unsigned short* __restrict__ e0,
                                                  const unsigned short* __restrict__ e1,
                                                  const unsigned short* __restrict__ e2,
                                                  const unsigned short* __restrict__ a0,
                                                  const unsigned short* __restrict__ a1,
                                                  const unsigned short* __restrict__ a2,
                                                  const short* __restrict__ W1t,
                                                  float* __restrict__ Pe, float* __restrict__ Pa) {
    __shared__ __align__(16) short As[128][40];
    __shared__ __align__(16) short Bs[64][40];
    const bool isPa = blockIdx.x >= 16;
    const unsigned short* S0 = isPa ? a0 : e0;
    const unsigned short* S1 = isPa ? a1 : e1;
    const unsigned short* S2 = isPa ? a2 : e2;
    const int M = isPa ? N_ * A_ : N_ * E_;
    const int r0 = (isPa ? blockIdx.x - 16 : blockIdx.x) * 128;
    float* C = isPa ? Pa : Pe;
    const int off0 = isPa ? 1 * D_ : 0, off1 = isPa ? 4 * D_ : 2 * D_, off2 = isPa ? 5 * D_ : 3 * D_;
    const int c0 = blockIdx.y * 64;
    const int tid = threadIdx.x;
    const int wave = tid >> 6, lane = tid & 63;
    const int row16 = lane & 15, quad = lane >> 4;
    f32x4v acc[2][4] = {};
    for (int k0 = 0; k0 < 3 * D_; k0 += 32) {
        const int seg = k0 / D_;
        const int kk = k0 - seg * D_;
        const unsigned short* Aseg = seg == 0 ? S0 : (seg == 1 ? S1 : S2);
        const int kg = (seg == 0 ? off0 : (seg == 1 ? off1 : off2)) + kk;
#pragma unroll
        for (int i = 0; i < 2; ++i) {
            const int idx = tid + 256 * i;
            const int r = idx >> 2, q = idx & 3;
            bshort8 av = {};
            if (r0 + r < M) av = *reinterpret_cast<const bshort8*>(Aseg + (size_t)(r0 + r) * D_ + kk + q * 8);
            *reinterpret_cast<bshort8*>(&As[r][q * 8]) = av;
        }
        {
            const int col = tid >> 2, q = tid & 3;
            *reinterpret_cast<bshort8*>(&Bs[col][q * 8]) =
                *reinterpret_cast<const bshort8*>(W1t + (size_t)(c0 + col) * W1R + kg + q * 8);
        }
        __syncthreads();
        bshort8 a[2], b[4];
#pragma unroll
        for (int mi = 0; mi < 2; ++mi)
            a[mi] = *reinterpret_cast<const bshort8*>(&As[wave * 32 + mi * 16 + row16][quad * 8]);
#pragma unroll
        for (int ni = 0; ni < 4; ++ni)
            b[ni] = *reinterpret_cast<const bshort8*>(&Bs[ni * 16 + row16][quad * 8]);
#pragma unroll
        for (int mi = 0; mi < 2; ++mi)
#pragma unroll
            for (int ni = 0; ni < 4; ++ni)
                acc[mi][ni] = __builtin_amdgcn_mfma_f32_16x16x32_bf16(a[mi], b[ni], acc[mi][ni], 0, 0, 0);
        __syncthreads();
    }
#pragma unroll
    for (int mi = 0; mi < 2; ++mi) {
#pragma unroll
        for (int ni = 0; ni < 4; ++ni) {
            const int rbase = r0 + wave * 32 + mi * 16 + quad * 4;
            const int col = c0 + ni * 16 + row16;
#pragma unroll
            for (int t = 0; t < 4; ++t)
                if (rbase + t < M) C[(size_t)(rbase + t) * H_ + col] = acc[mi][ni][t];
        }
    }
}

// ---- epilogue: gelu(Pe+Pa+b1)@W2 + b2, scatter ----
__global__ __launch_bounds__(256) void score_k(const float* __restrict__ Pe, const float* __restrict__ Pa,
                                               const float* __restrict__ b1, const float* __restrict__ W2,
                                               const float* __restrict__ b2, const int* __restrict__ arg_map,
                                               float* __restrict__ out) {
    const int n = blockIdx.x >> 7, e = blockIdx.x & 127;
    const int tid = threadIdx.x;
    __shared__ float paS[A_ * H_];
    __shared__ float part[A_][4];
    float* orow = out + ((size_t)(n * E_ + e)) * RO_;
    if (tid < RO_) orow[tid] = -1000000.0f;
    for (int i = tid; i < A_ * H_; i += 256) paS[i] = Pa[(size_t)n * A_ * H_ + i];
    __syncthreads();
    const float* per = Pe + ((size_t)(n * E_ + e)) * H_;
    float acc[A_] = {};
    for (int h = tid; h < H_; h += 256) {
        const float pe = per[h] + b1[h];
        const float w2 = W2[h];
#pragma unroll
        for (int a = 0; a < A_; ++a) {
            const float x = pe + paS[a * H_ + h];
            const float g = x * 0.5f * (1.0f + erff(x * 0.70710678118654752f));
            acc[a] = fmaf(g, w2, acc[a]);
        }
    }
    const int lane = tid & 63, wv = tid >> 6;
#pragma unroll
    for (int a = 0; a < A_; ++a)
        for (int off = 32; off; off >>= 1) acc[a] += __shfl_down(acc[a], off, 64);
    if (lane == 0)
        for (int a = 0; a < A_; ++a) part[a][wv] = acc[a];
    __syncthreads();
    if (tid < A_) {
        const float s = part[tid][0] + part[tid][1] + part[tid][2] + part[tid][3] + b2[0];
        orow[arg_map[n * A_ + tid]] = s;
    }
}

extern "C" void kernel_launch(void* const* d_in, const int* in_sizes, int n_in,
                              void* d_out, int out_size, void* d_ws, size_t ws_size,
                              hipStream_t stream) {
    const float* all_emb = (const float*)d_in[0];
    const float* attn    = (const float*)d_in[1];
    const float* ent_map = (const float*)d_in[2];
    const float* argw    = (const float*)d_in[3];
    // d_in[4] is_triggers unused (reference dead code)
    const float* W1 = (const float*)d_in[5];
    const float* b1 = (const float*)d_in[6];
    const float* W2 = (const float*)d_in[7];
    const float* b2 = (const float*)d_in[8];
    const int* idxs    = (const int*)d_in[9];
    const int* arg_map = (const int*)d_in[10];
    float* out = (float*)d_out;

    float* ws = (float*)d_ws;
    // fp32 buffers (float offsets)
    float* entf = ws + 0;               // N*E*D = 1,572,864
    float* Pe   = ws + 1572864;         // N*E*H = 1,572,864
    float* argE = ws + 3145728;         // N*A*D = 110,592
    float* wbuf = ws + 3256320;         // N*E*A = 18,432
    float* Pa   = ws + 3274752;         // N*A*H = 110,592
    // bf16 buffers (sizes in float-slots = shorts/2)
    short*          W1t     = (short*)(ws + 3385344);          // 768*4608
    unsigned short* sentT   = (unsigned short*)(ws + 5154816); // N*D*S
    unsigned short* entmapT = (unsigned short*)(ws + 5941248); // N*E*S
    unsigned short* t2tbf   = (unsigned short*)(ws + 6072320); // N*S*S
    unsigned short* argEbf  = (unsigned short*)(ws + 6127616); // N*A*D
    unsigned short* u2ubf   = (unsigned short*)(ws + 6182912); // N*A*D
    unsigned short* entbf   = (unsigned short*)(ws + 6238208); // N*E*D
    unsigned short* h2hT    = (unsigned short*)(ws + 7024640); // N*D*S
    unsigned short* Ah2hbf  = (unsigned short*)(ws + 7811072); // N*E*D
    unsigned short* tokAbf  = (unsigned short*)(ws + 8597504); // N*E*D
    unsigned short* argTbf  = (unsigned short*)(ws + 9383936); // N*A*D
    // total ≈ 9,439,232 floats = 37.8 MB

    // stage 1: layout transforms + gathers (independent)
    gatherT_k<<<dim3(N_, D_ / 64), 256, 0, stream>>>(all_emb, idxs, sentT);
    entmapT_k<<<N_, 256, 0, stream>>>(ent_map, entmapT);
    transpose_w1_k<<<dim3(W1R / 64, H_ / 64), 256, 0, stream>>>(W1, W1t);
    t2t_k<<<N_ * S_, 128, 0, stream>>>(attn, idxs, t2tbf);
    arg_u2u_k<<<N_, 256, 0, stream>>>(all_emb, idxs, argw, argE, argEbf, u2ubf);

    // stage 2: batched MFMA GEMMs
    dim3 gg(D_ / 64, N_);
    // h2hT[d][s] = (t2t @ sent)^T
    gemm128_k<1><<<gg, 256, 0, stream>>>(t2tbf, sentT, nullptr, h2hT);
    // ent = ent_map^T @ sent (fp32 + bf16)
    gemm128_k<0><<<gg, 256, 0, stream>>>(entmapT, sentT, entf, entbf);
    // Ah2h = ent_map^T @ h2h (bf16)
    gemm128_k<2><<<gg, 256, 0, stream>>>(entmapT, h2hT, nullptr, Ah2hbf);

    // stage 3: interactions
    w_tokA_k<<<N_ * E_, 256, 0, stream>>>(entf, argE, wbuf, tokAbf);
    argT_k<<<N_ * A_, 256, 0, stream>>>(wbuf, entf, argTbf);

    // stage 4: MLP layer 1 (Pe + Pa in one launch)
    // W1 row blocks: [ent 0 | argE 768 | tokA 1536 | Ah2h 2304 | argT 3072 | u2u 3840]
    mfma_mlp_k<<<dim3(18, H_ / 64), 256, 0, stream>>>(entbf, tokAbf, Ah2hbf, argEbf, argTbf, u2ubf, W1t, Pe, Pa);

    // stage 5: gelu + W2 + scatter
    score_k<<<N_ * E_, 256, 0, stream>>>(Pe, Pa, b1, W2, b2, arg_map, out);

    (void)in_sizes; (void)n_in; (void)out_size; (void)ws_size;
}